// Round 14
// baseline (56.384 us; speedup 1.0000x reference)
//
#include <hip/hip_runtime.h>
#include <stdint.h>

#define NB 8
#define NT 2048
#define NC 1024
#define HD 64

typedef __attribute__((ext_vector_type(8)))  short s16x8;
typedef __attribute__((ext_vector_type(4)))  float f32x4;
typedef __attribute__((ext_vector_type(16))) float f32x16;

__device__ inline ushort f2b(float f) {
    union { float f; uint32_t u; } c; c.f = f;
    uint32_t u = c.u;
    uint32_t r = (u + 0x7fffu + ((u >> 16) & 1u)) >> 16;   // RNE, finite inputs
    return (ushort)r;
}

__device__ inline uint32_t cvt_pk_bf16(float lo, float hi) {
    uint32_t r;
    asm("v_cvt_pk_bf16_f32 %0, %1, %2" : "=v"(r) : "v"(lo), "v"(hi));
    return r;
}

__device__ inline void gload_lds16(const void* gsrc, void* lds) {
    __builtin_amdgcn_global_load_lds(
        (const __attribute__((address_space(1))) void*)gsrc,
        (__attribute__((address_space(3))) void*)lds, 16, 0, 0);
}

// ---------------------------------------------------------------------------
// Kernel 0: W [1024][192] f32  ->  Wt [192][1024] bf16, q-cols pre-scaled by
// 0.125 * log2(e) so attention logits are already base-2.
// ---------------------------------------------------------------------------
__global__ __launch_bounds__(256) void wprep(const float* __restrict__ W,
                                             ushort* __restrict__ wt) {
    int tid = blockIdx.x * 256 + threadIdx.x;   // 192*1024 total
    int n = tid >> 10;          // 0..191 (output col of qkv)
    int k = tid & 1023;         // 0..1023
    float v = W[k * 192 + n];
    if (n < 64) v *= 0.125f * 1.4426950408889634f;
    wt[n * 1024 + k] = f2b(v);
}

// ---------------------------------------------------------------------------
// Kernel 1: qkv = x @ W.  BARRIER-FREE K-loop + A-staged-once.
// grid 256 (1 block/CU), 4 waves. Block = 64 rows x all 192 cols.
// Phase 1 (once): stage A = 64 rows x 1024 k as bf16 into 128 KB LDS,
//   granule-XOR swizzle (slot = g ^ 2*(row&7)); ONE barrier.
// Phase 2 (16 steps, NO barriers): wave wv owns cols wv*48..+48.
//   W-frags stream global->regs via inline-asm global_load_dwordx4 with
//   literal offset (compiler cannot demote the prefetch: R2/R5 lesson),
//   double-buffered wfA/wfB, counted vmcnt(6), sched_barrier(0) fences
//   (rule #18). A-frags: 1 ds_read_b128 each, pre-converted bf16.
//   Per wave-step: 8 ds_read + 24 MFMA (16x16x32). Waves free-run (R7
//   mechanism) -> L2 latency of W covered by phase drift + 2-step prefetch.
// ---------------------------------------------------------------------------
#define WL_(dst, base, OFF) \
    asm volatile("global_load_dwordx4 %0, %1, off offset:" #OFF \
                 : "=&v"(dst) : "v"(base))
#define WL(dst, base, OFF) WL_(dst, base, OFF)

#define WSET(WF, OFF) \
    WL(WF[0][0], wb00, OFF); WL(WF[0][1], wb01, OFF); \
    WL(WF[1][0], wb10, OFF); WL(WF[1][1], wb11, OFF); \
    WL(WF[2][0], wb20, OFF); WL(WF[2][1], wb21, OFF)

__global__ __launch_bounds__(256, 1) void qkv_gemm(const float* __restrict__ x,
                                                   const ushort* __restrict__ wt,
                                                   ushort* __restrict__ qs,
                                                   ushort* __restrict__ kk,
                                                   ushort* __restrict__ vt) {
    __shared__ __align__(16) char Alds[131072];   // [64 rows][128 granules x 16B]

    const int tid = threadIdx.x;
    const int wv  = tid >> 6;         // 0..3
    const int ls  = tid & 63;
    const int r16 = ls & 15;
    const int hi4 = ls >> 4;          // 0..3
    const int row0 = blockIdx.x * 64;
    const int b    = row0 >> 11;
    const int rloc = row0 & (NT - 1);

    // ---- Phase 1: stage A (64 rows x 1024 f32 -> bf16, swizzled) ----
    {
#pragma unroll
        for (int i = 0; i < 16; ++i) {
            int pidx = i * 256 + tid;           // 0..4095
            int row  = pidx >> 6;               // 0..63
            int p    = pidx & 63;               // 64B source chunk in row
            const float* src = x + (size_t)(row0 + row) * NC + p * 16;
            float4 f0 = *(const float4*)(src);
            float4 f1 = *(const float4*)(src + 4);
            float4 f2 = *(const float4*)(src + 8);
            float4 f3 = *(const float4*)(src + 12);
            union { uint32_t w[4]; s16x8 v; } g0, g1;
            g0.w[0] = cvt_pk_bf16(f0.x, f0.y);
            g0.w[1] = cvt_pk_bf16(f0.z, f0.w);
            g0.w[2] = cvt_pk_bf16(f1.x, f1.y);
            g0.w[3] = cvt_pk_bf16(f1.z, f1.w);
            g1.w[0] = cvt_pk_bf16(f2.x, f2.y);
            g1.w[1] = cvt_pk_bf16(f2.z, f2.w);
            g1.w[2] = cvt_pk_bf16(f3.x, f3.y);
            g1.w[3] = cvt_pk_bf16(f3.z, f3.w);
            int slot = (2 * p) ^ (2 * (row & 7));     // even-aligned pair slot
            *(s16x8*)(&Alds[row * 2048 + slot * 16])      = g0.v;
            *(s16x8*)(&Alds[row * 2048 + slot * 16 + 16]) = g1.v;
        }
    }

    // ---- per-lane constants ----
    const int akey = 2 * (r16 & 7);
    int abase[4];
#pragma unroll
    for (int m = 0; m < 4; ++m) abase[m] = (m * 16 + r16) * 2048;

    // W fragment base addresses (R2-verified layout): col = wv*48+nf*16+r16,
    // elem offset kq*32 + hi4*8; step t adds t*64 elems = t*128 bytes (imm).
    const ushort* wb00 = wt + (size_t)(wv * 48 + 0 * 16 + r16) * 1024 + 0 * 32 + hi4 * 8;
    const ushort* wb01 = wt + (size_t)(wv * 48 + 0 * 16 + r16) * 1024 + 1 * 32 + hi4 * 8;
    const ushort* wb10 = wt + (size_t)(wv * 48 + 1 * 16 + r16) * 1024 + 0 * 32 + hi4 * 8;
    const ushort* wb11 = wt + (size_t)(wv * 48 + 1 * 16 + r16) * 1024 + 1 * 32 + hi4 * 8;
    const ushort* wb20 = wt + (size_t)(wv * 48 + 2 * 16 + r16) * 1024 + 0 * 32 + hi4 * 8;
    const ushort* wb21 = wt + (size_t)(wv * 48 + 2 * 16 + r16) * 1024 + 1 * 32 + hi4 * 8;

    f32x4 acc[4][3];
#pragma unroll
    for (int m = 0; m < 4; ++m)
#pragma unroll
        for (int nf = 0; nf < 3; ++nf)
#pragma unroll
            for (int e = 0; e < 4; ++e) acc[m][nf][e] = 0.f;

    s16x8 wfA[3][2], wfB[3][2];

#define COMP(T, WF) do {                                                      \
    _Pragma("unroll")                                                         \
    for (int kq = 0; kq < 2; ++kq) {                                          \
        s16x8 af[4];                                                          \
        _Pragma("unroll")                                                     \
        for (int m = 0; m < 4; ++m) {                                         \
            int g = ((T) * 8 + kq * 4 + hi4) ^ akey;                          \
            af[m] = *(const s16x8*)(&Alds[abase[m] + g * 16]);                \
        }                                                                     \
        _Pragma("unroll")                                                     \
        for (int m = 0; m < 4; ++m)                                           \
            _Pragma("unroll")                                                 \
            for (int nf = 0; nf < 3; ++nf)                                    \
                acc[m][nf] = __builtin_amdgcn_mfma_f32_16x16x32_bf16(         \
                    af[m], WF[nf][kq], acc[m][nf], 0, 0, 0);                  \
    }                                                                         \
} while (0)

#define DSTEP(T, OFFA, OFFB)                                                  \
    asm volatile("s_waitcnt vmcnt(6)" ::: "memory");                          \
    __builtin_amdgcn_sched_barrier(0);                                        \
    COMP(T, wfA);                                                             \
    WSET(wfA, OFFA);                                                          \
    asm volatile("s_waitcnt vmcnt(6)" ::: "memory");                          \
    __builtin_amdgcn_sched_barrier(0);                                        \
    COMP((T) + 1, wfB);                                                       \
    WSET(wfB, OFFB);

    // barrier: A image complete (also drains phase-1 loads)
    __syncthreads();

    // prologue W loads: t=0 -> wfA, t=1 -> wfB  (12 outstanding)
    WSET(wfA, 0);
    WSET(wfB, 128);

    DSTEP(0,  256,  384)
    DSTEP(2,  512,  640)
    DSTEP(4,  768,  896)
    DSTEP(6,  1024, 1152)
    DSTEP(8,  1280, 1408)
    DSTEP(10, 1536, 1664)
    DSTEP(12, 1792, 1920)
    // tail: t=14 (wfA ready when 6 left), t=15 (drain)
    asm volatile("s_waitcnt vmcnt(6)" ::: "memory");
    __builtin_amdgcn_sched_barrier(0);
    COMP(14, wfA);
    asm volatile("s_waitcnt vmcnt(0)" ::: "memory");
    __builtin_amdgcn_sched_barrier(0);
    COMP(15, wfB);

#undef DSTEP
#undef COMP

    // ---- epilogue: scatter to qs / kk / vt(bf16, transposed) ----
#pragma unroll
    for (int m = 0; m < 4; ++m) {
        const int rbase = row0 + m * 16 + hi4 * 4;
#pragma unroll
        for (int nf = 0; nf < 3; ++nf) {
            int colg = wv * 48 + nf * 16 + r16;   // 0..191
            f32x4 v = acc[m][nf];
            if (colg < 64) {
#pragma unroll
                for (int j = 0; j < 4; ++j)
                    qs[(size_t)(rbase + j) * HD + colg] = f2b(v[j]);
            } else if (colg < 128) {
#pragma unroll
                for (int j = 0; j < 4; ++j)
                    kk[(size_t)(rbase + j) * HD + (colg - 64)] = f2b(v[j]);
            } else {
                int d = colg - 128;
                union { ushort4 s; ushort u[4]; } pk;
#pragma unroll
                for (int j = 0; j < 4; ++j) pk.u[j] = f2b(v[j]);
                *(ushort4*)(&vt[((size_t)(b * 64 + d)) * NT
                                + ((rloc + m * 16 + hi4 * 4) )]) = pk.s;
            }
        }
    }
}

// ---------------------------------------------------------------------------
// Kernel 2: causal flash attention. 8 waves/block, intra-block split-K:
// wave w handles k-tiles w, w+8, ... of its 32-row q-tile; partial
// (m,l,o) merged in LDS with exp2 rescaling. grid = 512, big tiles first.
// [VERIFIED R13 VERSION]
// ---------------------------------------------------------------------------
__global__ __launch_bounds__(512) void attn(const ushort* __restrict__ qs,
                                            const ushort* __restrict__ kk,
                                            const ushort* __restrict__ vt,
                                            float* __restrict__ out) {
    __shared__ float ob[8][64][33];   // per-wave unnormalized O^T partials
    __shared__ float ml[8][2][32];    // per-wave m / lsum per q col

    const int bid  = blockIdx.x;
    const int b    = bid & 7;
    const int tile = 63 - (bid >> 3);          // big-first for balance
    const int tid  = threadIdx.x;
    const int wv   = tid >> 6;                 // 0..7  (k-split index)
    const int l    = tid & 63;
    const int qcol = l & 31;
    const int hi   = l >> 5;
    const int r0   = tile * 32;

    const ushort* qb = qs + ((size_t)(b * NT + r0)) * HD;
    const ushort* kb = kk + (size_t)b * NT * HD;
    const ushort* vb = vt + (size_t)b * HD * NT;

    s16x8 qf[4];
#pragma unroll
    for (int c = 0; c < 4; ++c)
        qf[c] = *(const s16x8*)(qb + (size_t)qcol * HD + c * 16 + hi * 8);

    f32x16 o0, o1;
#pragma unroll
    for (int i = 0; i < 16; ++i) { o0[i] = 0.f; o1[i] = 0.f; }
    float m = -3.0e30f, lsum = 0.f;

    if (wv <= tile) {
        s16x8 kf[4], vf[4];
        {
            const ushort* kr = kb + (size_t)(wv * 32 + qcol) * HD;
#pragma unroll
            for (int c = 0; c < 4; ++c)
                kf[c] = *(const s16x8*)(kr + c * 16 + hi * 8);
#pragma unroll
            for (int dt = 0; dt < 2; ++dt)
#pragma unroll
                for (int kc = 0; kc < 2; ++kc)
                    vf[dt * 2 + kc] = *(const s16x8*)(vb + (size_t)(dt * 32 + qcol) * NT
                                                      + wv * 32 + kc * 16 + hi * 8);
        }

        for (int kt = wv; kt <= tile; kt += 8) {
            // S^T = K . Q^T   (col = q, row-regs = k_local)
            f32x16 s;
#pragma unroll
            for (int i = 0; i < 16; ++i) s[i] = 0.f;
#pragma unroll
            for (int c = 0; c < 4; ++c)
                s = __builtin_amdgcn_mfma_f32_32x32x16_bf16(kf[c], qf[c], s, 0, 0, 0);

            // prefetch this wave's next K/V tiles (stride 8)
            s16x8 kfn[4], vfn[4];
            const bool more = (kt + 8 <= tile);
            if (more) {
                const ushort* kr = kb + (size_t)((kt + 8) * 32 + qcol) * HD;
#pragma unroll
                for (int c = 0; c < 4; ++c)
                    kfn[c] = *(const s16x8*)(kr + c * 16 + hi * 8);
#pragma unroll
                for (int dt = 0; dt < 2; ++dt)
#pragma unroll
                    for (int kc = 0; kc < 2; ++kc)
                        vfn[dt * 2 + kc] = *(const s16x8*)(vb + (size_t)(dt * 32 + qcol) * NT
                                                           + (kt + 8) * 32 + kc * 16 + hi * 8);
            }

            // online softmax (per-lane scalar state: one q per lane)
            const bool diag = (kt == tile);
            float p[16];
#pragma unroll
            for (int r = 0; r < 16; ++r) {
                int klocal = (r & 3) + 8 * (r >> 2) + 4 * hi;
                float sv = s[r];
                if (diag && klocal > qcol) sv = -3.0e30f;
                p[r] = sv;
            }
            float pmax = p[0];
#pragma unroll
            for (int r = 1; r < 16; ++r) pmax = fmaxf(pmax, p[r]);
            pmax = fmaxf(pmax, __shfl_xor(pmax, 32));
            float mnew = fmaxf(m, pmax);
            float corr = exp2f(m - mnew);
            m = mnew;
            float rs = 0.f;
#pragma unroll
            for (int r = 0; r < 16; ++r) { p[r] = exp2f(p[r] - mnew); rs += p[r]; }
            rs += __shfl_xor(rs, 32);
            lsum = lsum * corr + rs;
#pragma unroll
            for (int i = 0; i < 16; ++i) { o0[i] *= corr; o1[i] *= corr; }

            // P (f32, S^T layout) -> bf16 B-fragments via cvt_pk + lane^32 exchange
#pragma unroll
            for (int kc = 0; kc < 2; ++kc) {
                int pb = kc * 8;
                uint32_t a0 = cvt_pk_bf16(p[pb + 0], p[pb + 1]);
                uint32_t a1 = cvt_pk_bf16(p[pb + 2], p[pb + 3]);
                uint32_t b0 = cvt_pk_bf16(p[pb + 4], p[pb + 5]);
                uint32_t b1 = cvt_pk_bf16(p[pb + 6], p[pb + 7]);
                uint32_t a0x = __shfl_xor(a0, 32);
                uint32_t a1x = __shfl_xor(a1, 32);
                uint32_t b0x = __shfl_xor(b0, 32);
                uint32_t b1x = __shfl_xor(b1, 32);
                union { uint32_t w[4]; s16x8 v; } frag;
                frag.w[0] = hi ? b0x : a0;
                frag.w[1] = hi ? b1x : a1;
                frag.w[2] = hi ? b0  : a0x;
                frag.w[3] = hi ? b1  : a1x;
                o0 = __builtin_amdgcn_mfma_f32_32x32x16_bf16(vf[0 * 2 + kc], frag.v, o0, 0, 0, 0);
                o1 = __builtin_amdgcn_mfma_f32_32x32x16_bf16(vf[1 * 2 + kc], frag.v, o1, 0, 0, 0);
            }

            if (more) {
#pragma unroll
                for (int c = 0; c < 4; ++c) kf[c] = kfn[c];
#pragma unroll
                for (int c = 0; c < 4; ++c) vf[c] = vfn[c];
            }
        }
    }

    // --- write per-wave partials (unnormalized) ---
#pragma unroll
    for (int r = 0; r < 16; ++r) {
        int d = (r & 3) + 8 * (r >> 2) + 4 * hi;
        ob[wv][d][qcol]      = o0[r];
        ob[wv][d + 32][qcol] = o1[r];
    }
    if (hi == 0) {
        ml[wv][0][qcol] = m;
        ml[wv][1][qcol] = lsum;
    }
    __syncthreads();

    // --- merge 8 partials + coalesced f32 store ---
    const int q  = tid >> 4;          // 0..31
    const int j0 = (tid & 15) * 4;    // 0..60
    float mwv[8];
#pragma unroll
    for (int w = 0; w < 8; ++w) mwv[w] = ml[w][0][q];
    float M = mwv[0];
#pragma unroll
    for (int w = 1; w < 8; ++w) M = fmaxf(M, mwv[w]);
    float sw[8]; float L = 0.f;
#pragma unroll
    for (int w = 0; w < 8; ++w) {
        sw[w] = exp2f(mwv[w] - M);
        L += sw[w] * ml[w][1][q];
    }
    float invL = 1.0f / L;
    float vals[4];
#pragma unroll
    for (int j = 0; j < 4; ++j) {
        int d = j0 + j;
        float acc = 0.f;
#pragma unroll
        for (int w = 0; w < 8; ++w) acc += sw[w] * ob[w][d][q];
        vals[j] = acc * invL;
    }
    float* orow = out + ((size_t)(b * NT + r0 + q)) * HD + j0;
    *(float4*)(orow) = make_float4(vals[0], vals[1], vals[2], vals[3]);
}

// ---------------------------------------------------------------------------
extern "C" void kernel_launch(void* const* d_in, const int* in_sizes, int n_in,
                              void* d_out, int out_size, void* d_ws, size_t ws_size,
                              hipStream_t stream) {
    const float* x = (const float*)d_in[0];
    const float* W = (const float*)d_in[1];
    float* out = (float*)d_out;

    ushort* qs = (ushort*)d_ws;                 // [8][2048][64] bf16 (pre-scaled q)
    ushort* kk = qs + (size_t)NB * NT * HD;     // [8][2048][64]
    ushort* vt = kk + (size_t)NB * NT * HD;     // [8][64][2048]  (V transposed)
    ushort* wt = vt + (size_t)NB * NT * HD;     // [192][1024]    (W^T bf16)

    wprep<<<768, 256, 0, stream>>>(W, wt);
    qkv_gemm<<<256, 256, 0, stream>>>(x, wt, qs, kk, vt);
    attn<<<512, 512, 0, stream>>>(qs, kk, vt, out);
}

// Round 17
// 50.748 us; speedup vs baseline: 1.1111x; 1.1111x over previous
//
#include <hip/hip_runtime.h>
#include <stdint.h>

#define NB 8
#define NT 2048
#define NC 1024
#define HD 64

typedef __attribute__((ext_vector_type(8)))  short s16x8;
typedef __attribute__((ext_vector_type(4)))  float f32x4;
typedef __attribute__((ext_vector_type(16))) float f32x16;

__device__ inline ushort f2b(float f) {
    union { float f; uint32_t u; } c; c.f = f;
    uint32_t u = c.u;
    uint32_t r = (u + 0x7fffu + ((u >> 16) & 1u)) >> 16;   // RNE, finite inputs
    return (ushort)r;
}

__device__ inline uint32_t cvt_pk_bf16(float lo, float hi) {
    uint32_t r;
    asm("v_cvt_pk_bf16_f32 %0, %1, %2" : "=v"(r) : "v"(lo), "v"(hi));
    return r;
}

__device__ inline void gload_lds16(const void* gsrc, void* lds) {
    __builtin_amdgcn_global_load_lds(
        (const __attribute__((address_space(1))) void*)gsrc,
        (__attribute__((address_space(3))) void*)lds, 16, 0, 0);
}

// ---------------------------------------------------------------------------
// Kernel 0: W [1024][192] f32  ->  Wt [192][1024] bf16, q-cols pre-scaled by
// 0.125 * log2(e) so attention logits are already base-2.
// ---------------------------------------------------------------------------
__global__ __launch_bounds__(256) void wprep(const float* __restrict__ W,
                                             ushort* __restrict__ wt) {
    int tid = blockIdx.x * 256 + threadIdx.x;   // 192*1024 total
    int n = tid >> 10;          // 0..191 (output col of qkv)
    int k = tid & 1023;         // 0..1023
    float v = W[k * 192 + n];
    if (n < 64) v *= 0.125f * 1.4426950408889634f;
    wt[n * 1024 + k] = f2b(v);
}

// ---------------------------------------------------------------------------
// Kernel 1: qkv = x @ W.  [VERIFIED R10/R13 VERSION — reverted after three
// failed step-count-reduction attempts (R14 regression, R15 flaky race,
// R16 NaN). This is the session's verified plateau for the GEMM.]
// BM=32, BN=96, BK=64, 4 waves, grid 1024 (512 rowtiles x 2 cg), 40KB LDS
// -> 4 blocks/CU. 2 LDS buffers, vmcnt(0) -> barrier -> STAGE(t+1) ->
// COMPUTE(t). global_load_lds(16B), contiguity-preserving swizzle.
// ---------------------------------------------------------------------------
__global__ __launch_bounds__(256, 4) void qkv_gemm(const float* __restrict__ x,
                                                   const ushort* __restrict__ wt,
                                                   ushort* __restrict__ qs,
                                                   ushort* __restrict__ kk,
                                                   ushort* __restrict__ vt) {
    __shared__ __align__(16) char Al[2][8192];    // [32 rows][16 slots x 16B] f32
    __shared__ __align__(16) char Wl[2][12288];   // [96 rows][8 slots x 16B] bf16

    const int tid = threadIdx.x;
    const int wv  = tid >> 6;         // 0..3
    const int ls  = tid & 63;
    const int r16 = ls & 15;
    const int hi4 = ls >> 4;          // 0..3
    const int bid = blockIdx.x;
    const int rowtile = bid & 511;
    const int cg  = bid >> 9;         // 0/1: cols cg*96..+96
    const int row0 = rowtile * 32;
    const int g   = wv >> 1;          // rowgroup 0..1 (16 rows)
    const int c   = wv & 1;           // colgroup 0..1 (48 cols)

    // ---- A staging sources: 2 instrs/wave, each 4 rows x 256B ----
    const float* xsrc[2];
#pragma unroll
    for (int j = 0; j < 2; ++j) {
        int r = (wv * 2 + j) * 4 + (ls >> 4);           // 0..31
        int slot = (ls & 15) ^ (r & 7);                 // in-row swizzle
        xsrc[j] = x + (size_t)(row0 + r) * NC + slot * 4;
    }
    // ---- W staging sources: 3 instrs/wave, each 8 rows x 128B ----
    const ushort* wsrc[3];
#pragma unroll
    for (int j = 0; j < 3; ++j) {
        int n = (wv * 3 + j) * 8 + (ls >> 3);           // 0..95 local col
        int slot = (ls & 7) ^ (n & 7);
        wsrc[j] = wt + (size_t)(cg * 96 + n) * 1024 + slot * 8;
    }

    // ---- ds_read offsets ----
    const int key = r16 & 7;
    const int arow = g * 16 + r16;
    int aoff[2];                                        // a1 = a0 ^ 16
#pragma unroll
    for (int kq = 0; kq < 2; ++kq)
        aoff[kq] = arow * 256 + (((kq * 8 + hi4 * 2) ^ key) << 4);
    int bnrow[3];
#pragma unroll
    for (int nf = 0; nf < 3; ++nf)
        bnrow[nf] = (c * 48 + nf * 16 + r16) * 128;
    int bkey[2];
#pragma unroll
    for (int kq = 0; kq < 2; ++kq)
        bkey[kq] = (((kq * 4 + hi4) ^ key) << 4);

    f32x4 acc[3];
#pragma unroll
    for (int j = 0; j < 3; ++j)
#pragma unroll
        for (int e = 0; e < 4; ++e) acc[j][e] = 0.f;

    auto STAGE = [&](int t) {
        int bb = t & 1;
#pragma unroll
        for (int j = 0; j < 2; ++j)
            gload_lds16(xsrc[j] + t * 64, &Al[bb][(wv * 2 + j) * 1024]);
#pragma unroll
        for (int j = 0; j < 3; ++j)
            gload_lds16(wsrc[j] + t * 64, &Wl[bb][(wv * 3 + j) * 1024]);
    };

    auto COMPUTE = [&](int bb) {
#pragma unroll
        for (int kq = 0; kq < 2; ++kq) {
            float4 a0 = *(const float4*)(&Al[bb][0] + aoff[kq]);
            float4 a1 = *(const float4*)(&Al[bb][0] + (aoff[kq] ^ 16));
            union { uint32_t w[4]; s16x8 v; } pk;
            pk.w[0] = cvt_pk_bf16(a0.x, a0.y);
            pk.w[1] = cvt_pk_bf16(a0.z, a0.w);
            pk.w[2] = cvt_pk_bf16(a1.x, a1.y);
            pk.w[3] = cvt_pk_bf16(a1.z, a1.w);
            s16x8 af = pk.v;
            s16x8 bf[3];
#pragma unroll
            for (int nf = 0; nf < 3; ++nf)
                bf[nf] = *(const s16x8*)(&Wl[bb][0] + bnrow[nf] + bkey[kq]);
#pragma unroll
            for (int nf = 0; nf < 3; ++nf)
                acc[nf] = __builtin_amdgcn_mfma_f32_16x16x32_bf16(
                    af, bf[nf], acc[nf], 0, 0, 0);
        }
    };

    // ---- prologue ----
    STAGE(0);

    // ---- main loop: 16 K-steps ----
    for (int t = 0; t < 16; ++t) {
        asm volatile("s_waitcnt vmcnt(0)" ::: "memory");   // stage t landed
        __builtin_amdgcn_s_barrier();                      // buf[t^1] readers done
        if (t < 15) STAGE(t + 1);
        COMPUTE(t & 1);
    }

    // ---- epilogue: scatter to qs / kk / vt(bf16, transposed) ----
    const int b = row0 >> 11;
    const int rbase = row0 + g * 16 + hi4 * 4;
#pragma unroll
    for (int nf = 0; nf < 3; ++nf) {
        int colg = cg * 96 + c * 48 + nf * 16 + r16;   // 0..191
        f32x4 v = acc[nf];
        if (colg < 64) {
#pragma unroll
            for (int j = 0; j < 4; ++j)
                qs[(size_t)(rbase + j) * HD + colg] = f2b(v[j]);
        } else if (colg < 128) {
#pragma unroll
            for (int j = 0; j < 4; ++j)
                kk[(size_t)(rbase + j) * HD + (colg - 64)] = f2b(v[j]);
        } else {
            int d = colg - 128;
            union { ushort4 s; ushort u[4]; } pk;
#pragma unroll
            for (int j = 0; j < 4; ++j) pk.u[j] = f2b(v[j]);
            *(ushort4*)(&vt[((size_t)(b * 64 + d)) * NT + (rbase & (NT - 1))]) = pk.s;
        }
    }
}

// ---------------------------------------------------------------------------
// Kernel 2: causal flash attention. 8 waves/block, intra-block split-K:
// wave w handles k-tiles w, w+8, ... of its 32-row q-tile; partial
// (m,l,o) merged in LDS with exp2 rescaling. grid = 512, big tiles first.
// [VERIFIED R13 VERSION]
// ---------------------------------------------------------------------------
__global__ __launch_bounds__(512) void attn(const ushort* __restrict__ qs,
                                            const ushort* __restrict__ kk,
                                            const ushort* __restrict__ vt,
                                            float* __restrict__ out) {
    __shared__ float ob[8][64][33];   // per-wave unnormalized O^T partials
    __shared__ float ml[8][2][32];    // per-wave m / lsum per q col

    const int bid  = blockIdx.x;
    const int b    = bid & 7;
    const int tile = 63 - (bid >> 3);          // big-first for balance
    const int tid  = threadIdx.x;
    const int wv   = tid >> 6;                 // 0..7  (k-split index)
    const int l    = tid & 63;
    const int qcol = l & 31;
    const int hi   = l >> 5;
    const int r0   = tile * 32;

    const ushort* qb = qs + ((size_t)(b * NT + r0)) * HD;
    const ushort* kb = kk + (size_t)b * NT * HD;
    const ushort* vb = vt + (size_t)b * HD * NT;

    s16x8 qf[4];
#pragma unroll
    for (int c = 0; c < 4; ++c)
        qf[c] = *(const s16x8*)(qb + (size_t)qcol * HD + c * 16 + hi * 8);

    f32x16 o0, o1;
#pragma unroll
    for (int i = 0; i < 16; ++i) { o0[i] = 0.f; o1[i] = 0.f; }
    float m = -3.0e30f, lsum = 0.f;

    if (wv <= tile) {
        s16x8 kf[4], vf[4];
        {
            const ushort* kr = kb + (size_t)(wv * 32 + qcol) * HD;
#pragma unroll
            for (int c = 0; c < 4; ++c)
                kf[c] = *(const s16x8*)(kr + c * 16 + hi * 8);
#pragma unroll
            for (int dt = 0; dt < 2; ++dt)
#pragma unroll
                for (int kc = 0; kc < 2; ++kc)
                    vf[dt * 2 + kc] = *(const s16x8*)(vb + (size_t)(dt * 32 + qcol) * NT
                                                      + wv * 32 + kc * 16 + hi * 8);
        }

        for (int kt = wv; kt <= tile; kt += 8) {
            // S^T = K . Q^T   (col = q, row-regs = k_local)
            f32x16 s;
#pragma unroll
            for (int i = 0; i < 16; ++i) s[i] = 0.f;
#pragma unroll
            for (int c = 0; c < 4; ++c)
                s = __builtin_amdgcn_mfma_f32_32x32x16_bf16(kf[c], qf[c], s, 0, 0, 0);

            // prefetch this wave's next K/V tiles (stride 8)
            s16x8 kfn[4], vfn[4];
            const bool more = (kt + 8 <= tile);
            if (more) {
                const ushort* kr = kb + (size_t)((kt + 8) * 32 + qcol) * HD;
#pragma unroll
                for (int c = 0; c < 4; ++c)
                    kfn[c] = *(const s16x8*)(kr + c * 16 + hi * 8);
#pragma unroll
                for (int dt = 0; dt < 2; ++dt)
#pragma unroll
                    for (int kc = 0; kc < 2; ++kc)
                        vfn[dt * 2 + kc] = *(const s16x8*)(vb + (size_t)(dt * 32 + qcol) * NT
                                                           + (kt + 8) * 32 + kc * 16 + hi * 8);
            }

            // online softmax (per-lane scalar state: one q per lane)
            const bool diag = (kt == tile);
            float p[16];
#pragma unroll
            for (int r = 0; r < 16; ++r) {
                int klocal = (r & 3) + 8 * (r >> 2) + 4 * hi;
                float sv = s[r];
                if (diag && klocal > qcol) sv = -3.0e30f;
                p[r] = sv;
            }
            float pmax = p[0];
#pragma unroll
            for (int r = 1; r < 16; ++r) pmax = fmaxf(pmax, p[r]);
            pmax = fmaxf(pmax, __shfl_xor(pmax, 32));
            float mnew = fmaxf(m, pmax);
            float corr = exp2f(m - mnew);
            m = mnew;
            float rs = 0.f;
#pragma unroll
            for (int r = 0; r < 16; ++r) { p[r] = exp2f(p[r] - mnew); rs += p[r]; }
            rs += __shfl_xor(rs, 32);
            lsum = lsum * corr + rs;
#pragma unroll
            for (int i = 0; i < 16; ++i) { o0[i] *= corr; o1[i] *= corr; }

            // P (f32, S^T layout) -> bf16 B-fragments via cvt_pk + lane^32 exchange
#pragma unroll
            for (int kc = 0; kc < 2; ++kc) {
                int pb = kc * 8;
                uint32_t a0 = cvt_pk_bf16(p[pb + 0], p[pb + 1]);
                uint32_t a1 = cvt_pk_bf16(p[pb + 2], p[pb + 3]);
                uint32_t b0 = cvt_pk_bf16(p[pb + 4], p[pb + 5]);
                uint32_t b1 = cvt_pk_bf16(p[pb + 6], p[pb + 7]);
                uint32_t a0x = __shfl_xor(a0, 32);
                uint32_t a1x = __shfl_xor(a1, 32);
                uint32_t b0x = __shfl_xor(b0, 32);
                uint32_t b1x = __shfl_xor(b1, 32);
                union { uint32_t w[4]; s16x8 v; } frag;
                frag.w[0] = hi ? b0x : a0;
                frag.w[1] = hi ? b1x : a1;
                frag.w[2] = hi ? b0  : a0x;
                frag.w[3] = hi ? b1  : a1x;
                o0 = __builtin_amdgcn_mfma_f32_32x32x16_bf16(vf[0 * 2 + kc], frag.v, o0, 0, 0, 0);
                o1 = __builtin_amdgcn_mfma_f32_32x32x16_bf16(vf[1 * 2 + kc], frag.v, o1, 0, 0, 0);
            }

            if (more) {
#pragma unroll
                for (int c = 0; c < 4; ++c) kf[c] = kfn[c];
#pragma unroll
                for (int c = 0; c < 4; ++c) vf[c] = vfn[c];
            }
        }
    }

    // --- write per-wave partials (unnormalized) ---
#pragma unroll
    for (int r = 0; r < 16; ++r) {
        int d = (r & 3) + 8 * (r >> 2) + 4 * hi;
        ob[wv][d][qcol]      = o0[r];
        ob[wv][d + 32][qcol] = o1[r];
    }
    if (hi == 0) {
        ml[wv][0][qcol] = m;
        ml[wv][1][qcol] = lsum;
    }
    __syncthreads();

    // --- merge 8 partials + coalesced f32 store ---
    const int q  = tid >> 4;          // 0..31
    const int j0 = (tid & 15) * 4;    // 0..60
    float mwv[8];
#pragma unroll
    for (int w = 0; w < 8; ++w) mwv[w] = ml[w][0][q];
    float M = mwv[0];
#pragma unroll
    for (int w = 1; w < 8; ++w) M = fmaxf(M, mwv[w]);
    float sw[8]; float L = 0.f;
#pragma unroll
    for (int w = 0; w < 8; ++w) {
        sw[w] = exp2f(mwv[w] - M);
        L += sw[w] * ml[w][1][q];
    }
    float invL = 1.0f / L;
    float vals[4];
#pragma unroll
    for (int j = 0; j < 4; ++j) {
        int d = j0 + j;
        float acc = 0.f;
#pragma unroll
        for (int w = 0; w < 8; ++w) acc += sw[w] * ob[w][d][q];
        vals[j] = acc * invL;
    }
    float* orow = out + ((size_t)(b * NT + r0 + q)) * HD + j0;
    *(float4*)(orow) = make_float4(vals[0], vals[1], vals[2], vals[3]);
}

// ---------------------------------------------------------------------------
extern "C" void kernel_launch(void* const* d_in, const int* in_sizes, int n_in,
                              void* d_out, int out_size, void* d_ws, size_t ws_size,
                              hipStream_t stream) {
    const float* x = (const float*)d_in[0];
    const float* W = (const float*)d_in[1];
    float* out = (float*)d_out;

    ushort* qs = (ushort*)d_ws;                 // [8][2048][64] bf16 (pre-scaled q)
    ushort* kk = qs + (size_t)NB * NT * HD;     // [8][2048][64]
    ushort* vt = kk + (size_t)NB * NT * HD;     // [8][64][2048]  (V transposed)
    ushort* wt = vt + (size_t)NB * NT * HD;     // [192][1024]    (W^T bf16)

    wprep<<<768, 256, 0, stream>>>(W, wt);
    qkv_gemm<<<1024, 256, 0, stream>>>(x, wt, qs, kk, vt);
    attn<<<512, 512, 0, stream>>>(qs, kk, vt, out);
}